// Round 2
// baseline (820.536 us; speedup 1.0000x reference)
//
#include <hip/hip_runtime.h>

#define N_TOK 4096
#define C_IN 256
#define CI_ 128

typedef unsigned short u16;
typedef unsigned int   u32;

// ---- bf16 helpers (OCP bf16 = upper 16 bits of fp32) ----
__device__ __forceinline__ float lo16f(u32 u){ union{u32 i; float f;} c; c.i = u << 16; return c.f; }
__device__ __forceinline__ float hi16f(u32 u){ union{u32 i; float f;} c; c.i = u & 0xffff0000u; return c.f; }
__device__ __forceinline__ void bf8f(const uint4 u, float* f){
    f[0]=lo16f(u.x); f[1]=hi16f(u.x); f[2]=lo16f(u.y); f[3]=hi16f(u.y);
    f[4]=lo16f(u.z); f[5]=hi16f(u.z); f[6]=lo16f(u.w); f[7]=hi16f(u.w);
}
__device__ __forceinline__ float bf1f(u16 v){ union{u32 i; float f;} c; c.i = ((u32)v)<<16; return c.f; }
__device__ __forceinline__ u16 f2bf(float f){
    union{float f; u32 i;} c; c.f = f;
    u32 i = c.i;
    u32 r = (i + 0x7fffu + ((i >> 16) & 1u)) >> 16;   // RNE
    return (u16)r;
}

// dtype-robust 8-element load (idx must be 8-aligned in elements)
__device__ __forceinline__ void load8(const void* base, size_t idx, int flag, float* f){
    if (flag) {   // fp32 data
        const float* p = (const float*)base + idx;
        *(float4*)&f[0] = *(const float4*)p;
        *(float4*)&f[4] = *(const float4*)(p + 4);
    } else {      // bf16 data
        uint4 u = *(const uint4*)((const u16*)base + idx);
        bf8f(u, f);
    }
}

// =====================================================================
// Detect input dtype from w_g (std=0.01 weights).
// If fp32: even u16s are mantissa bits -> ~50% have bf16-exponent >= 128.
// If bf16: |w| ~ 0.04 max -> exponent >= 128 never.
// flag = 1 -> fp32 inputs, 0 -> bf16 inputs.
// =====================================================================
__global__ __launch_bounds__(64) void detect_kernel(const u16* __restrict__ wg, int* __restrict__ flag)
{
    int lane = threadIdx.x;
    int cnt = 0;
    for (int i = lane; i < 256; i += 64) {
        u16 v = wg[2 * i];
        if (((v >> 7) & 0xFF) >= 128) cnt++;
    }
    #pragma unroll
    for (int off = 32; off; off >>= 1) cnt += __shfl_down(cnt, off);
    if (lane == 0) *flag = (cnt >= 8) ? 1 : 0;
}

// =====================================================================
// Canonicalize the 10 small params to fp32 at fixed offsets.
// wg 0, wt 32768, wp 65536, wo 98304, bg 131072, bt 131200, bp 131328,
// bo 131456, gm 131712, bt2 131968, total 132224.
// =====================================================================
__global__ __launch_bounds__(256) void convert_params_kernel(
    const void* wg, const void* wt, const void* wp, const void* wo,
    const void* bg, const void* bt, const void* bp, const void* bo,
    const void* gm, const void* bt2,
    const int* __restrict__ flag, float* __restrict__ canon)
{
    int idx = blockIdx.x * 256 + threadIdx.x;
    if (idx >= 132224) return;
    int f = *flag;
    const void* src; int loc;
    if      (idx < 32768)  { src = wg;  loc = idx; }
    else if (idx < 65536)  { src = wt;  loc = idx - 32768; }
    else if (idx < 98304)  { src = wp;  loc = idx - 65536; }
    else if (idx < 131072) { src = wo;  loc = idx - 98304; }
    else if (idx < 131200) { src = bg;  loc = idx - 131072; }
    else if (idx < 131328) { src = bt;  loc = idx - 131200; }
    else if (idx < 131456) { src = bp;  loc = idx - 131328; }
    else if (idx < 131712) { src = bo;  loc = idx - 131456; }
    else if (idx < 131968) { src = gm;  loc = idx - 131712; }
    else                   { src = bt2; loc = idx - 131968; }
    canon[idx] = f ? ((const float*)src)[loc] : bf1f(((const u16*)src)[loc]);
}

// =====================================================================
// Kernel A: fused projections g/theta/phi (weights from fp32 canon).
// proj[b][r][n] = sum_k w[r][k] * x[b][k][n] + bias[r]
// grid (ntile=64, mtile=6, b=4), block 256. 64x64 tile, K-chunks of 32.
// =====================================================================
__global__ __launch_bounds__(256) void proj_kernel(
    const void* __restrict__ x, const float* __restrict__ canon,
    const int* __restrict__ flagp,
    float* __restrict__ gbuf, float* __restrict__ tbuf, float* __restrict__ pbuf)
{
    const int flag = *flagp;
    const int b  = blockIdx.z;
    const int r0 = blockIdx.y * 64;
    const int n0 = blockIdx.x * 64;
    const int tid = threadIdx.x;
    const int pidx = r0 >> 7;
    const float* w   = canon + (size_t)pidx * 32768;
    const float* bia = canon + 131072 + (size_t)pidx * 128;
    float* dst       = (pidx == 0) ? gbuf : (pidx == 1 ? tbuf : pbuf);
    const int rl0 = r0 & 127;

    __shared__ float At[32][68];   // [k][r]
    __shared__ float Xt[32][64];   // [k][n]
    const int tx = tid & 15, ty = tid >> 4;
    float acc[4][4] = {};
    const size_t xb_off = (size_t)b * C_IN * N_TOK;

    for (int k0 = 0; k0 < C_IN; k0 += 32) {
        __syncthreads();
        {   // W tile: 64 rows x 32 k, fp32 canon, transpose-store
            int r  = tid >> 2;
            int k8 = (tid & 3) * 8;
            const float* p = &w[(size_t)(rl0 + r) * C_IN + k0 + k8];
            float f[8];
            *(float4*)&f[0] = *(const float4*)p;
            *(float4*)&f[4] = *(const float4*)(p + 4);
            #pragma unroll
            for (int i = 0; i < 8; ++i) At[k8 + i][r] = f[i];
        }
        {   // X tile: 32 k x 64 n (dtype-robust load)
            int kk = tid >> 3;
            int n8 = (tid & 7) * 8;
            float f[8];
            load8(x, xb_off + (size_t)(k0 + kk) * N_TOK + n0 + n8, flag, f);
            *(float4*)&Xt[kk][n8]     = *(float4*)&f[0];
            *(float4*)&Xt[kk][n8 + 4] = *(float4*)&f[4];
        }
        __syncthreads();
        #pragma unroll
        for (int k = 0; k < 32; ++k) {
            float a[4], xv[4];
            *(float4*)a  = *(const float4*)&At[k][ty * 4];
            *(float4*)xv = *(const float4*)&Xt[k][tx * 4];
            #pragma unroll
            for (int i = 0; i < 4; ++i)
                #pragma unroll
                for (int j = 0; j < 4; ++j)
                    acc[i][j] = fmaf(a[i], xv[j], acc[i][j]);
        }
    }
    #pragma unroll
    for (int i = 0; i < 4; ++i) {
        int r = ty * 4 + i;
        float bv = bia[rl0 + r];
        float4 v = make_float4(acc[i][0] + bv, acc[i][1] + bv, acc[i][2] + bv, acc[i][3] + bv);
        *(float4*)&dst[((size_t)b * CI_ + rl0 + r) * N_TOK + n0 + tx * 4] = v;
    }
}

// =====================================================================
// Kernel B: flash attention per batch (fp32 in ws, unchanged math).
// grid (qtile=128, b=4), block 128. TQ=32, TM=64.
// =====================================================================
__global__ __launch_bounds__(128) void attn_kernel(
    const float* __restrict__ tbuf, const float* __restrict__ pbuf,
    const float* __restrict__ gbuf, float* __restrict__ yt)
{
    const int b  = blockIdx.y;
    const int q0 = blockIdx.x * 32;
    const int tid = threadIdx.x;
    const int tx = tid & 15, ty = tid >> 4;

    const float* th = tbuf + (size_t)b * CI_ * N_TOK;
    const float* ph = pbuf + (size_t)b * CI_ * N_TOK;
    const float* gg = gbuf + (size_t)b * CI_ * N_TOK;

    __shared__ float Th[CI_][32];
    __shared__ float PhG[64 * 129];
    __shared__ float Sm[32 * 65];
    __shared__ float alphaS[32];
    __shared__ float lS[32];

    {   // stage theta tile once: [128][32]
        int c = tid >> 3, q4 = (tid & 7) * 4;
        #pragma unroll
        for (int p = 0; p < 8; ++p)
            *(float4*)&Th[c + p * 16][q4] =
                *(const float4*)&th[(size_t)(c + p * 16) * N_TOK + q0 + q4];
    }

    float acc[4][8] = {};
    float m_st = -3.0e38f, l_st = 0.f;
    const int sq = tid >> 2, spart = tid & 3;

    for (int t = 0; t < 64; ++t) {
        const int m0 = t * 64;
        __syncthreads();
        {   // stage phi tile [128][64]
            int c = tid >> 4, m4 = (tid & 15) * 4;
            #pragma unroll
            for (int p = 0; p < 16; ++p)
                *(float4*)&PhG[(c + p * 8) * 64 + m4] =
                    *(const float4*)&ph[(size_t)(c + p * 8) * N_TOK + m0 + m4];
        }
        __syncthreads();
        // ---- S phase ----
        float s[4][4] = {};
        #pragma unroll 8
        for (int k = 0; k < CI_; ++k) {
            float a[4], bb[4];
            *(float4*)a  = *(const float4*)&Th[k][ty * 4];
            *(float4*)bb = *(const float4*)&PhG[k * 64 + tx * 4];
            #pragma unroll
            for (int i = 0; i < 4; ++i)
                #pragma unroll
                for (int j = 0; j < 4; ++j)
                    s[i][j] = fmaf(a[i], bb[j], s[i][j]);
        }
        #pragma unroll
        for (int i = 0; i < 4; ++i)
            #pragma unroll
            for (int j = 0; j < 4; ++j)
                Sm[(ty * 4 + i) * 65 + tx * 4 + j] = s[i][j];
        __syncthreads();
        // ---- online softmax ----
        float* srow = &Sm[sq * 65 + spart * 16];
        float tmax = srow[0];
        #pragma unroll
        for (int mm = 1; mm < 16; ++mm) tmax = fmaxf(tmax, srow[mm]);
        tmax = fmaxf(tmax, __shfl_xor(tmax, 1));
        tmax = fmaxf(tmax, __shfl_xor(tmax, 2));
        float m_new = fmaxf(m_st, tmax);
        float alpha = __expf(m_st - m_new);
        float psum = 0.f;
        #pragma unroll
        for (int mm = 0; mm < 16; ++mm) {
            float pv = __expf(srow[mm] - m_new);
            srow[mm] = pv;
            psum += pv;
        }
        psum += __shfl_xor(psum, 1);
        psum += __shfl_xor(psum, 2);
        m_st = m_new;
        l_st = l_st * alpha + psum;
        if (spart == 0) alphaS[sq] = alpha;
        {   // stage G transposed: Gt[m][c], stride 129
            int c = tid >> 4, m4 = (tid & 15) * 4;
            #pragma unroll
            for (int p = 0; p < 16; ++p) {
                int cc = c + p * 8;
                float4 v = *(const float4*)&gg[(size_t)cc * N_TOK + m0 + m4];
                PhG[(m4 + 0) * 129 + cc] = v.x;
                PhG[(m4 + 1) * 129 + cc] = v.y;
                PhG[(m4 + 2) * 129 + cc] = v.z;
                PhG[(m4 + 3) * 129 + cc] = v.w;
            }
        }
        __syncthreads();
        // ---- PV phase ----
        float al[4];
        #pragma unroll
        for (int i = 0; i < 4; ++i) al[i] = alphaS[ty * 4 + i];
        #pragma unroll
        for (int i = 0; i < 4; ++i)
            #pragma unroll
            for (int j = 0; j < 8; ++j)
                acc[i][j] *= al[i];
        #pragma unroll 4
        for (int m = 0; m < 64; ++m) {
            float pq[4], gv[8];
            #pragma unroll
            for (int i = 0; i < 4; ++i) pq[i] = Sm[(ty * 4 + i) * 65 + m];
            #pragma unroll
            for (int j = 0; j < 8; ++j) gv[j] = PhG[m * 129 + j * 16 + tx];
            #pragma unroll
            for (int i = 0; i < 4; ++i)
                #pragma unroll
                for (int j = 0; j < 8; ++j)
                    acc[i][j] = fmaf(pq[i], gv[j], acc[i][j]);
        }
    }
    if (spart == 0) lS[sq] = 1.f / l_st;
    __syncthreads();
    #pragma unroll
    for (int i = 0; i < 4; ++i) {
        int q = ty * 4 + i;
        float li = lS[q];
        #pragma unroll
        for (int j = 0; j < 8; ++j)
            yt[((size_t)b * N_TOK + q0 + q) * CI_ + j * 16 + tx] = acc[i][j] * li;
    }
}

// =====================================================================
// Kernel C: W_y[b][o][n] = sum_ci w_out[o][ci] * yt[b][n][ci] + b_out[o]
// =====================================================================
__global__ __launch_bounds__(256) void outproj_kernel(
    const float* __restrict__ canon,
    const float* __restrict__ yt, float* __restrict__ wy)
{
    const float* w_out = canon + 98304;
    const float* b_out = canon + 131456;
    const int b  = blockIdx.z;
    const int o0 = blockIdx.y * 64;
    const int n0 = blockIdx.x * 64;
    const int tid = threadIdx.x;
    const int tx = tid & 15, ty = tid >> 4;
    __shared__ float At[32][68];
    __shared__ float Xt[32][68];
    float acc[4][4] = {};
    const float* ytb = yt + (size_t)b * N_TOK * CI_;

    for (int k0 = 0; k0 < CI_; k0 += 32) {
        __syncthreads();
        {   // w_out tile: 64 o x 32 k -> At[k][o]
            int r = tid >> 2, k8 = (tid & 3) * 8;
            const float* p = &w_out[(size_t)(o0 + r) * CI_ + k0 + k8];
            float f[8];
            *(float4*)&f[0] = *(const float4*)p;
            *(float4*)&f[4] = *(const float4*)(p + 4);
            #pragma unroll
            for (int i = 0; i < 8; ++i) At[k8 + i][r] = f[i];
        }
        {   // y tile: 64 n x 32 k -> Xt[k][n]
            int n = tid >> 3, k4 = (tid & 7) * 4;
            #pragma unroll
            for (int p = 0; p < 2; ++p) {
                float4 v = *(const float4*)&ytb[(size_t)(n0 + n + p * 32) * CI_ + k0 + k4];
                Xt[k4 + 0][n + p * 32] = v.x;
                Xt[k4 + 1][n + p * 32] = v.y;
                Xt[k4 + 2][n + p * 32] = v.z;
                Xt[k4 + 3][n + p * 32] = v.w;
            }
        }
        __syncthreads();
        #pragma unroll
        for (int k = 0; k < 32; ++k) {
            float a[4], xv[4];
            *(float4*)a  = *(const float4*)&At[k][ty * 4];
            *(float4*)xv = *(const float4*)&Xt[k][tx * 4];
            #pragma unroll
            for (int i = 0; i < 4; ++i)
                #pragma unroll
                for (int j = 0; j < 4; ++j)
                    acc[i][j] = fmaf(a[i], xv[j], acc[i][j]);
        }
    }
    #pragma unroll
    for (int i = 0; i < 4; ++i) {
        int o = o0 + ty * 4 + i;
        float bv = b_out[o];
        float4 v = make_float4(acc[i][0] + bv, acc[i][1] + bv, acc[i][2] + bv, acc[i][3] + bv);
        *(float4*)&wy[((size_t)b * C_IN + o) * N_TOK + n0 + tx * 4] = v;
    }
}

// =====================================================================
// Kernel C2: BN batch stats per channel (training mode, ddof=0), double accum.
// =====================================================================
__global__ __launch_bounds__(256) void bnstats_kernel(
    const float* __restrict__ wy, float* __restrict__ meanv, float* __restrict__ rstdv)
{
    const int o = blockIdx.x;
    const int tid = threadIdx.x;
    double s1 = 0.0, s2 = 0.0;
    for (int b = 0; b < 4; ++b) {
        const float* p = wy + ((size_t)b * C_IN + o) * N_TOK;
        for (int i = tid * 4; i < N_TOK; i += 1024) {
            float4 v = *(const float4*)&p[i];
            s1 += (double)v.x + (double)v.y + (double)v.z + (double)v.w;
            s2 += (double)v.x * v.x + (double)v.y * v.y + (double)v.z * v.z + (double)v.w * v.w;
        }
    }
    #pragma unroll
    for (int off = 32; off > 0; off >>= 1) {
        s1 += __shfl_down(s1, off);
        s2 += __shfl_down(s2, off);
    }
    __shared__ double red1[4], red2[4];
    int w = tid >> 6;
    if ((tid & 63) == 0) { red1[w] = s1; red2[w] = s2; }
    __syncthreads();
    if (tid == 0) {
        double a = red1[0] + red1[1] + red1[2] + red1[3];
        double q = red2[0] + red2[1] + red2[2] + red2[3];
        double mean = a * (1.0 / 16384.0);
        double var  = q * (1.0 / 16384.0) - mean * mean;
        meanv[o] = (float)mean;
        rstdv[o] = (float)(1.0 / sqrt(var + 1e-5));
    }
}

// =====================================================================
// Kernel D: out = (W_y - mean)*rstd*gamma + beta + x   (dtype-matched out)
// =====================================================================
__global__ __launch_bounds__(256) void bnorm_kernel(
    const float* __restrict__ wy, const void* __restrict__ x,
    const float* __restrict__ meanv, const float* __restrict__ rstdv,
    const float* __restrict__ canon, const int* __restrict__ flagp,
    void* __restrict__ outv)
{
    const int flag = *flagp;
    size_t base = ((size_t)blockIdx.x * 256 + threadIdx.x) * 8;
    int o = (int)((base >> 12) & 255);
    float m = meanv[o], r = rstdv[o];
    float gm = canon[131712 + o], bt = canon[131968 + o];
    float4 v0 = *(const float4*)&wy[base];
    float4 v1 = *(const float4*)&wy[base + 4];
    float xf[8]; load8(x, base, flag, xf);
    float ov[8];
    ov[0] = (v0.x - m) * r * gm + bt + xf[0];
    ov[1] = (v0.y - m) * r * gm + bt + xf[1];
    ov[2] = (v0.z - m) * r * gm + bt + xf[2];
    ov[3] = (v0.w - m) * r * gm + bt + xf[3];
    ov[4] = (v1.x - m) * r * gm + bt + xf[4];
    ov[5] = (v1.y - m) * r * gm + bt + xf[5];
    ov[6] = (v1.z - m) * r * gm + bt + xf[6];
    ov[7] = (v1.w - m) * r * gm + bt + xf[7];
    if (flag) {
        float* op = (float*)outv + base;
        *(float4*)op       = *(float4*)&ov[0];
        *(float4*)(op + 4) = *(float4*)&ov[4];
    } else {
        uint4 res;
        res.x = (u32)f2bf(ov[0]) | ((u32)f2bf(ov[1]) << 16);
        res.y = (u32)f2bf(ov[2]) | ((u32)f2bf(ov[3]) << 16);
        res.z = (u32)f2bf(ov[4]) | ((u32)f2bf(ov[5]) << 16);
        res.w = (u32)f2bf(ov[6]) | ((u32)f2bf(ov[7]) << 16);
        *(uint4*)((u16*)outv + base) = res;
    }
}

extern "C" void kernel_launch(void* const* d_in, const int* in_sizes, int n_in,
                              void* d_out, int out_size, void* d_ws, size_t ws_size,
                              hipStream_t stream)
{
    const void* x   = d_in[0];
    const void* w_g = d_in[1];
    const void* b_g = d_in[2];
    const void* w_t = d_in[3];
    const void* b_t = d_in[4];
    const void* w_p = d_in[5];
    const void* b_p = d_in[6];
    const void* w_o = d_in[7];
    const void* b_o = d_in[8];
    const void* gm  = d_in[9];
    const void* bt  = d_in[10];

    float* ws = (float*)d_ws;
    float* canon = ws;                         // 132224 floats
    int*   flagp = (int*)(ws + 132224);
    const size_t P = (size_t)4 * CI_ * N_TOK;  // 2,097,152
    float* gbuf  = ws + 133120;
    float* tbuf  = gbuf + P;
    float* pbuf  = tbuf + P;
    float* yt    = pbuf + P;
    float* wy    = gbuf;                       // alias: gbuf/tbuf dead after attn
    float* meanv = yt + P;
    float* rstdv = meanv + 256;

    detect_kernel<<<1, 64, 0, stream>>>((const u16*)w_g, flagp);
    convert_params_kernel<<<517, 256, 0, stream>>>(w_g, w_t, w_p, w_o, b_g, b_t, b_p, b_o,
                                                   gm, bt, flagp, canon);
    proj_kernel<<<dim3(64, 6, 4), 256, 0, stream>>>(x, canon, flagp, gbuf, tbuf, pbuf);
    attn_kernel<<<dim3(128, 4), 128, 0, stream>>>(tbuf, pbuf, gbuf, yt);
    outproj_kernel<<<dim3(64, 4, 4), 256, 0, stream>>>(canon, yt, wy);
    bnstats_kernel<<<256, 256, 0, stream>>>(wy, meanv, rstdv);
    bnorm_kernel<<<2048, 256, 0, stream>>>(wy, x, meanv, rstdv, canon, flagp, d_out);
}

// Round 3
// 248.191 us; speedup vs baseline: 3.3061x; 3.3061x over previous
//
#include <hip/hip_runtime.h>

#define N_TOK 4096
#define C_IN 256
#define CI_ 128

typedef unsigned short u16;
typedef unsigned int   u32;
typedef __attribute__((ext_vector_type(8))) short bf16x8;
typedef __attribute__((ext_vector_type(4))) float f32x4;

// ---- bf16 helpers ----
__device__ __forceinline__ float lo16f(u32 u){ union{u32 i; float f;} c; c.i = u << 16; return c.f; }
__device__ __forceinline__ float hi16f(u32 u){ union{u32 i; float f;} c; c.i = u & 0xffff0000u; return c.f; }
__device__ __forceinline__ void bf8f(const uint4 u, float* f){
    f[0]=lo16f(u.x); f[1]=hi16f(u.x); f[2]=lo16f(u.y); f[3]=hi16f(u.y);
    f[4]=lo16f(u.z); f[5]=hi16f(u.z); f[6]=lo16f(u.w); f[7]=hi16f(u.w);
}
__device__ __forceinline__ float bf1f(u16 v){ union{u32 i; float f;} c; c.i = ((u32)v)<<16; return c.f; }
__device__ __forceinline__ u16 f2bf(float f){
    union{float f; u32 i;} c; c.f = f;
    u32 i = c.i;
    u32 r = (i + 0x7fffu + ((i >> 16) & 1u)) >> 16;   // RNE
    return (u16)r;
}
__device__ __forceinline__ u32 packbf(float a, float b){
    return (u32)f2bf(a) | ((u32)f2bf(b) << 16);
}

__device__ __forceinline__ void load8(const void* base, size_t idx, int flag, float* f){
    if (flag) {
        const float* p = (const float*)base + idx;
        *(float4*)&f[0] = *(const float4*)p;
        *(float4*)&f[4] = *(const float4*)(p + 4);
    } else {
        uint4 u = *(const uint4*)((const u16*)base + idx);
        bf8f(u, f);
    }
}

// ===================== dtype detect =====================
__global__ __launch_bounds__(64) void detect_kernel(const u16* __restrict__ wg, int* __restrict__ flag)
{
    int lane = threadIdx.x;
    int cnt = 0;
    for (int i = lane; i < 256; i += 64) {
        u16 v = wg[2 * i];
        if (((v >> 7) & 0xFF) >= 128) cnt++;
    }
    #pragma unroll
    for (int off = 32; off; off >>= 1) cnt += __shfl_down(cnt, off);
    if (lane == 0) *flag = (cnt >= 8) ? 1 : 0;
}

// ===================== param canonicalize =====================
__global__ __launch_bounds__(256) void convert_params_kernel(
    const void* wg, const void* wt, const void* wp, const void* wo,
    const void* bg, const void* bt, const void* bp, const void* bo,
    const void* gm, const void* bt2,
    const int* __restrict__ flag, float* __restrict__ canon)
{
    int idx = blockIdx.x * 256 + threadIdx.x;
    if (idx >= 132224) return;
    int f = *flag;
    const void* src; int loc;
    if      (idx < 32768)  { src = wg;  loc = idx; }
    else if (idx < 65536)  { src = wt;  loc = idx - 32768; }
    else if (idx < 98304)  { src = wp;  loc = idx - 65536; }
    else if (idx < 131072) { src = wo;  loc = idx - 98304; }
    else if (idx < 131200) { src = bg;  loc = idx - 131072; }
    else if (idx < 131328) { src = bt;  loc = idx - 131200; }
    else if (idx < 131456) { src = bp;  loc = idx - 131328; }
    else if (idx < 131712) { src = bo;  loc = idx - 131456; }
    else if (idx < 131968) { src = gm;  loc = idx - 131712; }
    else                   { src = bt2; loc = idx - 131968; }
    canon[idx] = f ? ((const float*)src)[loc] : bf1f(((const u16*)src)[loc]);
}

// =====================================================================
// Kernel A: projections, fp32 math, bf16 outputs in MFMA-friendly layouts:
//   g     -> gbuf  [b][c][n]  bf16   (PV A-operand layout)
//   theta -> tbufT [b][n][c]  bf16   (QK^T B-operand layout)
//   phi   -> pbufT [b][n][c]  bf16   (QK^T A-operand layout)
// =====================================================================
__global__ __launch_bounds__(256) void proj_kernel(
    const void* __restrict__ x, const float* __restrict__ canon,
    const int* __restrict__ flagp,
    u16* __restrict__ gbuf, u16* __restrict__ tbufT, u16* __restrict__ pbufT)
{
    const int flag = *flagp;
    const int b  = blockIdx.z;
    const int r0 = blockIdx.y * 64;
    const int n0 = blockIdx.x * 64;
    const int tid = threadIdx.x;
    const int pidx = r0 >> 7;
    const float* w   = canon + (size_t)pidx * 32768;
    const float* bia = canon + 131072 + (size_t)pidx * 128;
    const int rl0 = r0 & 127;

    __shared__ float At[32][68];
    __shared__ float Xt[32][64];
    const int tx = tid & 15, ty = tid >> 4;
    float acc[4][4] = {};
    const size_t xb_off = (size_t)b * C_IN * N_TOK;

    for (int k0 = 0; k0 < C_IN; k0 += 32) {
        __syncthreads();
        {
            int r  = tid >> 2;
            int k8 = (tid & 3) * 8;
            const float* p = &w[(size_t)(rl0 + r) * C_IN + k0 + k8];
            float f[8];
            *(float4*)&f[0] = *(const float4*)p;
            *(float4*)&f[4] = *(const float4*)(p + 4);
            #pragma unroll
            for (int i = 0; i < 8; ++i) At[k8 + i][r] = f[i];
        }
        {
            int kk = tid >> 3;
            int n8 = (tid & 7) * 8;
            float f[8];
            load8(x, xb_off + (size_t)(k0 + kk) * N_TOK + n0 + n8, flag, f);
            *(float4*)&Xt[kk][n8]     = *(float4*)&f[0];
            *(float4*)&Xt[kk][n8 + 4] = *(float4*)&f[4];
        }
        __syncthreads();
        #pragma unroll
        for (int k = 0; k < 32; ++k) {
            float a[4], xv[4];
            *(float4*)a  = *(const float4*)&At[k][ty * 4];
            *(float4*)xv = *(const float4*)&Xt[k][tx * 4];
            #pragma unroll
            for (int i = 0; i < 4; ++i)
                #pragma unroll
                for (int j = 0; j < 4; ++j)
                    acc[i][j] = fmaf(a[i], xv[j], acc[i][j]);
        }
    }
    #pragma unroll
    for (int i = 0; i < 4; ++i) {
        float bv = bia[rl0 + ty * 4 + i];
        #pragma unroll
        for (int j = 0; j < 4; ++j) acc[i][j] += bv;
    }
    if (pidx == 0) {
        // g: [c][n], pack 4 n per row
        #pragma unroll
        for (int i = 0; i < 4; ++i) {
            int r = rl0 + ty * 4 + i;
            uint2 v;
            v.x = packbf(acc[i][0], acc[i][1]);
            v.y = packbf(acc[i][2], acc[i][3]);
            *(uint2*)&gbuf[((size_t)b * CI_ + r) * N_TOK + n0 + tx * 4] = v;
        }
    } else {
        u16* dst = (pidx == 1) ? tbufT : pbufT;
        // T layout: [n][c], pack 4 c per n
        #pragma unroll
        for (int j = 0; j < 4; ++j) {
            int n = n0 + tx * 4 + j;
            uint2 v;
            v.x = packbf(acc[0][j], acc[1][j]);
            v.y = packbf(acc[2][j], acc[3][j]);
            *(uint2*)&dst[((size_t)b * N_TOK + n) * CI_ + rl0 + ty * 4] = v;
        }
    }
}

// =====================================================================
// Kernel B: MFMA flash attention.
// Block: 512 thr = 8 waves = 4 q-waves (16 q each) x 2 m-parities. Q-tile 64.
// Computes S^T[m][q] = phi^T . theta (MFMA, A=PhT from LDS, B=theta regs),
// online softmax over m (row dim), P packed bf16 -> LDS -> PV B-frags,
// y^T[c][q] += G[c][m-chunk] . P^T  (A=G from LDS).
// Writes yt[b][n][c] fp32.
// LDS swizzles: XOR-chunk; G rows padded to 160B.
// =====================================================================
#define PH_OFF(p) ((p) * 16384)            // 2 x 16KB  [64 m][128 k] bf16, 256B rows
#define G_OFF(p)  (32768 + (p) * 20480)    // 2 x 20KB  [128 c][64 m] bf16, 160B rows
#define PB_OFF    73728                    // 8 x 2KB   per-wave P^T [16 q][64 m] bf16, 128B rows
#define MST_OFF   90112                    // 4*16 f32
#define LST_OFF   90368                    // 4*16 f32
#define SMEM_SZ   90624

__global__ __launch_bounds__(512) void attn_kernel(
    const u16* __restrict__ tbufT, const u16* __restrict__ pbufT,
    const u16* __restrict__ gbuf, float* __restrict__ yt)
{
    __shared__ __align__(16) char smem[SMEM_SZ];
    const int b   = blockIdx.y;
    const int q0  = blockIdx.x * 64;
    const int tid = threadIdx.x;
    const int w    = tid >> 6;
    const int lane = tid & 63;
    const int col  = lane & 15;     // q within 16-frag
    const int quad = lane >> 4;     // 0..3
    const int wq   = w & 3;         // q-wave index
    const int ms   = w >> 2;        // m-parity
    const int qw   = wq * 16;

    // theta B-frags (held in regs for whole kernel)
    bf16x8 thf[4];
    {
        const u16* tb = tbufT + ((size_t)b * N_TOK + q0 + qw + col) * CI_;
        #pragma unroll
        for (int kc = 0; kc < 4; ++kc)
            thf[kc] = *(const bf16x8*)(tb + kc * 32 + quad * 8);
    }

    f32x4 yacc[8];
    #pragma unroll
    for (int i = 0; i < 8; ++i) yacc[i] = (f32x4){0.f, 0.f, 0.f, 0.f};
    float m_st = -3.0e38f, l_st = 0.f;

    const size_t bN = (size_t)b * N_TOK;
    const size_t bC = (size_t)b * CI_;

    for (int s = 0; s < 32; ++s) {
        __syncthreads();
        // ---- stage Ph + G tiles for both parities ----
        #pragma unroll
        for (int p = 0; p < 2; ++p) {
            const int m0p = (2 * s + p) * 64;
            #pragma unroll
            for (int i = 0; i < 2; ++i) {
                int cid = i * 512 + tid;            // 0..1023
                int m = cid >> 4, h = cid & 15;
                uint4 v = *(const uint4*)(pbufT + (bN + m0p + m) * CI_ + h * 8);
                *(uint4*)(smem + PH_OFF(p) + m * 256 + ((h ^ (m & 15)) << 4)) = v;
            }
            #pragma unroll
            for (int i = 0; i < 2; ++i) {
                int cid = i * 512 + tid;
                int c = cid >> 3, h = cid & 7;
                uint4 v = *(const uint4*)(gbuf + (bC + c) * N_TOK + m0p + h * 8);
                *(uint4*)(smem + G_OFF(p) + c * 160 + ((h ^ (c & 7)) << 4)) = v;
            }
        }
        __syncthreads();

        // ---- S^T = PhT . theta ----
        f32x4 sacc[4];
        #pragma unroll
        for (int i = 0; i < 4; ++i) sacc[i] = (f32x4){0.f, 0.f, 0.f, 0.f};
        #pragma unroll
        for (int kc = 0; kc < 4; ++kc) {
            #pragma unroll
            for (int msub = 0; msub < 4; ++msub) {
                int m = msub * 16 + col;
                int h = kc * 4 + quad;
                bf16x8 af = *(const bf16x8*)(smem + PH_OFF(ms) + m * 256 + ((h ^ (m & 15)) << 4));
                sacc[msub] = __builtin_amdgcn_mfma_f32_16x16x32_bf16(af, thf[kc], sacc[msub], 0, 0, 0);
            }
        }

        // ---- online softmax over m (rows) for fixed q=col ----
        float tmax = sacc[0][0];
        #pragma unroll
        for (int i = 0; i < 4; ++i)
            #pragma unroll
            for (int r = 0; r < 4; ++r) tmax = fmaxf(tmax, sacc[i][r]);
        tmax = fmaxf(tmax, __shfl_xor(tmax, 16));
        tmax = fmaxf(tmax, __shfl_xor(tmax, 32));
        float m_new = fmaxf(m_st, tmax);
        float p16[16], ps = 0.f;
        #pragma unroll
        for (int i = 0; i < 4; ++i)
            #pragma unroll
            for (int r = 0; r < 4; ++r) {
                float pv = __expf(sacc[i][r] - m_new);
                p16[i * 4 + r] = pv;
                ps += pv;
            }
        ps += __shfl_xor(ps, 16);
        ps += __shfl_xor(ps, 32);
        float alpha = __expf(m_st - m_new);
        l_st = l_st * alpha + ps;
        m_st = m_new;
        #pragma unroll
        for (int i = 0; i < 8; ++i) {
            yacc[i][0] *= alpha; yacc[i][1] *= alpha; yacc[i][2] *= alpha; yacc[i][3] *= alpha;
        }

        // ---- pack P^T pairs (regs r,r+1 = consecutive m) -> swizzled LDS ----
        {
            char* pb = smem + PB_OFF + w * 2048 + col * 128;
            #pragma unroll
            for (int msub = 0; msub < 4; ++msub) {
                #pragma unroll
                for (int pr = 0; pr < 2; ++pr) {
                    u32 d = packbf(p16[msub * 4 + pr * 2], p16[msub * 4 + pr * 2 + 1]);
                    int h = msub * 2 + (quad >> 1);
                    *(u32*)(pb + ((h ^ (col & 7)) << 4) + (quad & 1) * 8 + pr * 4) = d;
                }
            }
        }
        __asm volatile("s_waitcnt lgkmcnt(0)" ::: "memory");

        // ---- PV: y^T[c][q] += G . P^T ----
        bf16x8 pf[2];
        #pragma unroll
        for (int km = 0; km < 2; ++km) {
            int h = km * 4 + quad;
            pf[km] = *(const bf16x8*)(smem + PB_OFF + w * 2048 + col * 128 + ((h ^ (col & 7)) << 4));
        }
        #pragma unroll
        for (int csub = 0; csub < 8; ++csub) {
            #pragma unroll
            for (int km = 0; km < 2; ++km) {
                int c = csub * 16 + col;
                int h = km * 4 + quad;
                bf16x8 gf = *(const bf16x8*)(smem + G_OFF(ms) + c * 160 + ((h ^ (c & 7)) << 4));
                yacc[csub] = __builtin_amdgcn_mfma_f32_16x16x32_bf16(gf, pf[km], yacc[csub], 0, 0, 0);
            }
        }
    }

    // ---- merge the two m-parity partials (pairs w, w+4) ----
    __syncthreads();
    if (ms == 1) {
        char* mb = smem + wq * 8192 + col * 512;
        #pragma unroll
        for (int csub = 0; csub < 8; ++csub)
            *(f32x4*)(mb + (((csub * 4 + quad) ^ col) << 4)) = yacc[csub];
        if (quad == 0) {
            *(float*)(smem + MST_OFF + (wq * 16 + col) * 4) = m_st;
            *(float*)(smem + LST_OFF + (wq * 16 + col) * 4) = l_st;
        }
    }
    __syncthreads();
    if (ms == 0) {
        float m1 = *(const float*)(smem + MST_OFF + (wq * 16 + col) * 4);
        float l1 = *(const float*)(smem + LST_OFF + (wq * 16 + col) * 4);
        float M  = fmaxf(m_st, m1);
        float a0 = __expf(m_st - M), a1 = __expf(m1 - M);
        float li = 1.f / (l_st * a0 + l1 * a1);
        float s0 = a0 * li, s1 = a1 * li;
        const char* mb = smem + wq * 8192 + col * 512;
        float* yo = yt + (bN + q0 + qw + col) * CI_ + quad * 4;
        #pragma unroll
        for (int csub = 0; csub < 8; ++csub) {
            f32x4 y1 = *(const f32x4*)(mb + (((csub * 4 + quad) ^ col) << 4));
            f32x4 r;
            r[0] = yacc[csub][0] * s0 + y1[0] * s1;
            r[1] = yacc[csub][1] * s0 + y1[1] * s1;
            r[2] = yacc[csub][2] * s0 + y1[2] * s1;
            r[3] = yacc[csub][3] * s0 + y1[3] * s1;
            *(f32x4*)(yo + csub * 16) = r;
        }
    }
}

// =====================================================================
// Kernel C: W_y[b][o][n] = sum_ci w_out[o][ci] * yt[b][n][ci] + b_out[o]
// =====================================================================
__global__ __launch_bounds__(256) void outproj_kernel(
    const float* __restrict__ canon,
    const float* __restrict__ yt, float* __restrict__ wy)
{
    const float* w_out = canon + 98304;
    const float* b_out = canon + 131456;
    const int b  = blockIdx.z;
    const int o0 = blockIdx.y * 64;
    const int n0 = blockIdx.x * 64;
    const int tid = threadIdx.x;
    const int tx = tid & 15, ty = tid >> 4;
    __shared__ float At[32][68];
    __shared__ float Xt[32][68];
    float acc[4][4] = {};
    const float* ytb = yt + (size_t)b * N_TOK * CI_;

    for (int k0 = 0; k0 < CI_; k0 += 32) {
        __syncthreads();
        {
            int r = tid >> 2, k8 = (tid & 3) * 8;
            const float* p = &w_out[(size_t)(o0 + r) * CI_ + k0 + k8];
            float f[8];
            *(float4*)&f[0] = *(const float4*)p;
            *(float4*)&f[4] = *(const float4*)(p + 4);
            #pragma unroll
            for (int i = 0; i < 8; ++i) At[k8 + i][r] = f[i];
        }
        {
            int n = tid >> 3, k4 = (tid & 7) * 4;
            #pragma unroll
            for (int p = 0; p < 2; ++p) {
                float4 v = *(const float4*)&ytb[(size_t)(n0 + n + p * 32) * CI_ + k0 + k4];
                Xt[k4 + 0][n + p * 32] = v.x;
                Xt[k4 + 1][n + p * 32] = v.y;
                Xt[k4 + 2][n + p * 32] = v.z;
                Xt[k4 + 3][n + p * 32] = v.w;
            }
        }
        __syncthreads();
        #pragma unroll
        for (int k = 0; k < 32; ++k) {
            float a[4], xv[4];
            *(float4*)a  = *(const float4*)&At[k][ty * 4];
            *(float4*)xv = *(const float4*)&Xt[k][tx * 4];
            #pragma unroll
            for (int i = 0; i < 4; ++i)
                #pragma unroll
                for (int j = 0; j < 4; ++j)
                    acc[i][j] = fmaf(a[i], xv[j], acc[i][j]);
        }
    }
    #pragma unroll
    for (int i = 0; i < 4; ++i) {
        int o = o0 + ty * 4 + i;
        float bv = b_out[o];
        float4 v = make_float4(acc[i][0] + bv, acc[i][1] + bv, acc[i][2] + bv, acc[i][3] + bv);
        *(float4*)&wy[((size_t)b * C_IN + o) * N_TOK + n0 + tx * 4] = v;
    }
}

// ===================== BN stats =====================
__global__ __launch_bounds__(256) void bnstats_kernel(
    const float* __restrict__ wy, float* __restrict__ meanv, float* __restrict__ rstdv)
{
    const int o = blockIdx.x;
    const int tid = threadIdx.x;
    double s1 = 0.0, s2 = 0.0;
    for (int b = 0; b < 4; ++b) {
        const float* p = wy + ((size_t)b * C_IN + o) * N_TOK;
        for (int i = tid * 4; i < N_TOK; i += 1024) {
            float4 v = *(const float4*)&p[i];
            s1 += (double)v.x + (double)v.y + (double)v.z + (double)v.w;
            s2 += (double)v.x * v.x + (double)v.y * v.y + (double)v.z * v.z + (double)v.w * v.w;
        }
    }
    #pragma unroll
    for (int off = 32; off > 0; off >>= 1) {
        s1 += __shfl_down(s1, off);
        s2 += __shfl_down(s2, off);
    }
    __shared__ double red1[4], red2[4];
    int w = tid >> 6;
    if ((tid & 63) == 0) { red1[w] = s1; red2[w] = s2; }
    __syncthreads();
    if (tid == 0) {
        double a = red1[0] + red1[1] + red1[2] + red1[3];
        double q = red2[0] + red2[1] + red2[2] + red2[3];
        double mean = a * (1.0 / 16384.0);
        double var  = q * (1.0 / 16384.0) - mean * mean;
        meanv[o] = (float)mean;
        rstdv[o] = (float)(1.0 / sqrt(var + 1e-5));
    }
}

// ===================== BN apply + residual =====================
__global__ __launch_bounds__(256) void bnorm_kernel(
    const float* __restrict__ wy, const void* __restrict__ x,
    const float* __restrict__ meanv, const float* __restrict__ rstdv,
    const float* __restrict__ canon, const int* __restrict__ flagp,
    void* __restrict__ outv)
{
    const int flag = *flagp;
    size_t base = ((size_t)blockIdx.x * 256 + threadIdx.x) * 8;
    int o = (int)((base >> 12) & 255);
    float m = meanv[o], r = rstdv[o];
    float gm = canon[131712 + o], bt = canon[131968 + o];
    float4 v0 = *(const float4*)&wy[base];
    float4 v1 = *(const float4*)&wy[base + 4];
    float xf[8]; load8(x, base, flag, xf);
    float ov[8];
    ov[0] = (v0.x - m) * r * gm + bt + xf[0];
    ov[1] = (v0.y - m) * r * gm + bt + xf[1];
    ov[2] = (v0.z - m) * r * gm + bt + xf[2];
    ov[3] = (v0.w - m) * r * gm + bt + xf[3];
    ov[4] = (v1.x - m) * r * gm + bt + xf[4];
    ov[5] = (v1.y - m) * r * gm + bt + xf[5];
    ov[6] = (v1.z - m) * r * gm + bt + xf[6];
    ov[7] = (v1.w - m) * r * gm + bt + xf[7];
    if (flag) {
        float* op = (float*)outv + base;
        *(float4*)op       = *(float4*)&ov[0];
        *(float4*)(op + 4) = *(float4*)&ov[4];
    } else {
        uint4 res;
        res.x = packbf(ov[0], ov[1]);
        res.y = packbf(ov[2], ov[3]);
        res.z = packbf(ov[4], ov[5]);
        res.w = packbf(ov[6], ov[7]);
        *(uint4*)((u16*)outv + base) = res;
    }
}

extern "C" void kernel_launch(void* const* d_in, const int* in_sizes, int n_in,
                              void* d_out, int out_size, void* d_ws, size_t ws_size,
                              hipStream_t stream)
{
    const void* x   = d_in[0];
    const void* w_g = d_in[1];
    const void* b_g = d_in[2];
    const void* w_t = d_in[3];
    const void* b_t = d_in[4];
    const void* w_p = d_in[5];
    const void* b_p = d_in[6];
    const void* w_o = d_in[7];
    const void* b_o = d_in[8];
    const void* gm  = d_in[9];
    const void* bt  = d_in[10];

    char* base = (char*)d_ws;
    float* canon = (float*)base;                       // 132224 f32
    int*   flagp = (int*)(base + 528896);
    u16*   gbuf  = (u16*)(base + 532480);              // 4 MB bf16 [b][c][n]
    u16*   tbufT = (u16*)(base + 4726784);             // 4 MB bf16 [b][n][c]
    u16*   pbufT = (u16*)(base + 8921088);             // 4 MB bf16 [b][n][c]
    float* yt    = (float*)(base + 13115392);          // 8 MB f32 [b][n][c]
    float* wy    = (float*)(base + 21504000);          // 16 MB f32 [b][o][n]
    float* meanv = (float*)(base + 38281216);
    float* rstdv = (float*)(base + 38282240);

    detect_kernel<<<1, 64, 0, stream>>>((const u16*)w_g, flagp);
    convert_params_kernel<<<517, 256, 0, stream>>>(w_g, w_t, w_p, w_o, b_g, b_t, b_p, b_o,
                                                   gm, bt, flagp, canon);
    proj_kernel<<<dim3(64, 6, 4), 256, 0, stream>>>(x, canon, flagp, gbuf, tbufT, pbufT);
    attn_kernel<<<dim3(64, 4), 512, 0, stream>>>(tbufT, pbufT, gbuf, yt);
    outproj_kernel<<<dim3(64, 4, 4), 256, 0, stream>>>(canon, yt, wy);
    bnstats_kernel<<<256, 256, 0, stream>>>(wy, meanv, rstdv);
    bnorm_kernel<<<2048, 256, 0, stream>>>(wy, x, meanv, rstdv, canon, flagp, d_out);
}

// Round 4
// 227.505 us; speedup vs baseline: 3.6067x; 1.0909x over previous
//
#include <hip/hip_runtime.h>

#define N_TOK 4096
#define C_IN 256
#define CI_ 128

typedef unsigned short u16;
typedef unsigned int   u32;
typedef __attribute__((ext_vector_type(8))) short bf16x8;
typedef __attribute__((ext_vector_type(4))) float f32x4;

// ---- bf16 helpers ----
__device__ __forceinline__ float lo16f(u32 u){ union{u32 i; float f;} c; c.i = u << 16; return c.f; }
__device__ __forceinline__ float hi16f(u32 u){ union{u32 i; float f;} c; c.i = u & 0xffff0000u; return c.f; }
__device__ __forceinline__ void bf8f(const uint4 u, float* f){
    f[0]=lo16f(u.x); f[1]=hi16f(u.x); f[2]=lo16f(u.y); f[3]=hi16f(u.y);
    f[4]=lo16f(u.z); f[5]=hi16f(u.z); f[6]=lo16f(u.w); f[7]=hi16f(u.w);
}
__device__ __forceinline__ float bf1f(u16 v){ union{u32 i; float f;} c; c.i = ((u32)v)<<16; return c.f; }
__device__ __forceinline__ u16 f2bf(float f){
    union{float f; u32 i;} c; c.f = f;
    u32 i = c.i;
    u32 r = (i + 0x7fffu + ((i >> 16) & 1u)) >> 16;   // RNE
    return (u16)r;
}
__device__ __forceinline__ u32 packbf(float a, float b){
    return (u32)f2bf(a) | ((u32)f2bf(b) << 16);
}

__device__ __forceinline__ void load8(const void* base, size_t idx, int flag, float* f){
    if (flag) {
        const float* p = (const float*)base + idx;
        *(float4*)&f[0] = *(const float4*)p;
        *(float4*)&f[4] = *(const float4*)(p + 4);
    } else {
        uint4 u = *(const uint4*)((const u16*)base + idx);
        bf8f(u, f);
    }
}

// ===================== dtype detect =====================
__global__ __launch_bounds__(64) void detect_kernel(const u16* __restrict__ wg, int* __restrict__ flag)
{
    int lane = threadIdx.x;
    int cnt = 0;
    for (int i = lane; i < 256; i += 64) {
        u16 v = wg[2 * i];
        if (((v >> 7) & 0xFF) >= 128) cnt++;
    }
    #pragma unroll
    for (int off = 32; off; off >>= 1) cnt += __shfl_down(cnt, off);
    if (lane == 0) *flag = (cnt >= 8) ? 1 : 0;
}

// ===================== param canonicalize (fp32 + bf16 weights) =====================
__global__ __launch_bounds__(256) void convert_params_kernel(
    const void* wg, const void* wt, const void* wp, const void* wo,
    const void* bg, const void* bt, const void* bp, const void* bo,
    const void* gm, const void* bt2,
    const int* __restrict__ flag, float* __restrict__ canon, u16* __restrict__ canon_bf)
{
    int idx = blockIdx.x * 256 + threadIdx.x;
    if (idx >= 132224) return;
    int f = *flag;
    const void* src; int loc;
    if      (idx < 32768)  { src = wg;  loc = idx; }
    else if (idx < 65536)  { src = wt;  loc = idx - 32768; }
    else if (idx < 98304)  { src = wp;  loc = idx - 65536; }
    else if (idx < 131072) { src = wo;  loc = idx - 98304; }
    else if (idx < 131200) { src = bg;  loc = idx - 131072; }
    else if (idx < 131328) { src = bt;  loc = idx - 131200; }
    else if (idx < 131456) { src = bp;  loc = idx - 131328; }
    else if (idx < 131712) { src = bo;  loc = idx - 131456; }
    else if (idx < 131968) { src = gm;  loc = idx - 131712; }
    else                   { src = bt2; loc = idx - 131968; }
    float v = f ? ((const float*)src)[loc] : bf1f(((const u16*)src)[loc]);
    canon[idx] = v;
    if (idx < 131072) canon_bf[idx] = f2bf(v);
}

// =====================================================================
// Kernel A: MFMA projections. C[r][n] = sum_k w[r][k]*x[b][k][n] + bias[r]
// r in [0,384): 0-127 g, 128-255 theta, 256-383 phi. K=256, chunks of 32.
// Block 256 thr (4 waves); n-tile 64; wave w handles r in [96w, 96w+96).
// B-frags: x^T staged in LDS [n][k^swz]; A-frags: direct from bf16 weights.
// Epilogue: C restaged via LDS [n][r] for coalesced bf16 stores:
//   gbuf [b][c][n], tbufT [b][n][c], pbufT [b][n][c].
// =====================================================================
__global__ __launch_bounds__(256) void proj_kernel(
    const void* __restrict__ x, const float* __restrict__ canon,
    const u16* __restrict__ wbf, const int* __restrict__ flagp,
    u16* __restrict__ gbuf, u16* __restrict__ tbufT, u16* __restrict__ pbufT)
{
    __shared__ __align__(16) u16 plds[64 * 400];   // 51200 B: xs=[64][40] in loop, cl=[64][400] epilogue
    const int flag = *flagp;
    const int b  = blockIdx.y;
    const int n0 = blockIdx.x * 64;
    const int tid = threadIdx.x;
    const int w    = tid >> 6;
    const int lane = tid & 63;
    const int col  = lane & 15;
    const int quad = lane >> 4;
    const int rw   = w * 96;

    f32x4 acc[6][4];
    #pragma unroll
    for (int i = 0; i < 6; ++i)
        #pragma unroll
        for (int j = 0; j < 4; ++j) acc[i][j] = (f32x4){0.f,0.f,0.f,0.f};

    const size_t xb = (size_t)b * C_IN * N_TOK;
    const int sk = tid >> 3;          // staging k 0..31
    const int sn8 = (tid & 7) * 8;    // staging n base

    for (int kc = 0; kc < 8; ++kc) {
        const int k0 = kc * 32;
        __syncthreads();
        {   // stage x^T [n][k] bf16, k swizzled by n-chunk
            float f[8];
            load8(x, xb + (size_t)(k0 + sk) * N_TOK + n0 + sn8, flag, f);
            #pragma unroll
            for (int i = 0; i < 8; ++i) {
                int n = sn8 + i;
                int kk = sk ^ (((n >> 3) & 3) << 3);
                plds[n * 40 + kk] = f2bf(f[i]);
            }
        }
        __syncthreads();
        bf16x8 bfr[4];
        #pragma unroll
        for (int nf = 0; nf < 4; ++nf) {
            int n = nf * 16 + col;
            int q2 = quad ^ ((n >> 3) & 3);
            bfr[nf] = *(const bf16x8*)&plds[n * 40 + q2 * 8];
        }
        #pragma unroll
        for (int rs = 0; rs < 6; ++rs) {
            bf16x8 afr = *(const bf16x8*)&wbf[(size_t)(rw + rs * 16 + col) * 256 + k0 + quad * 8];
            #pragma unroll
            for (int nf = 0; nf < 4; ++nf)
                acc[rs][nf] = __builtin_amdgcn_mfma_f32_16x16x32_bf16(afr, bfr[nf], acc[rs][nf], 0, 0, 0);
        }
    }

    // ---- bias + restage C to LDS cl[n][r] (rows padded to 400 u16) ----
    __syncthreads();
    #pragma unroll
    for (int rs = 0; rs < 6; ++rs) {
        int r0 = rw + rs * 16 + quad * 4;
        float b0 = canon[131072 + r0 + 0];
        float b1 = canon[131072 + r0 + 1];
        float b2 = canon[131072 + r0 + 2];
        float b3 = canon[131072 + r0 + 3];
        #pragma unroll
        for (int nf = 0; nf < 4; ++nf) {
            int n = nf * 16 + col;
            uint2 pv;
            pv.x = packbf(acc[rs][nf][0] + b0, acc[rs][nf][1] + b1);
            pv.y = packbf(acc[rs][nf][2] + b2, acc[rs][nf][3] + b3);
            *(uint2*)&plds[n * 400 + r0] = pv;
        }
    }
    __syncthreads();

    const size_t bN = (size_t)b * N_TOK;
    {   // gbuf [c][n]: r = tid&127, n-half = tid>>7
        int r = tid & 127, half = tid >> 7;
        u16 tmp[32];
        #pragma unroll
        for (int j = 0; j < 32; ++j) tmp[j] = plds[(half * 32 + j) * 400 + r];
        u16* dst = &gbuf[((size_t)b * CI_ + r) * N_TOK + n0 + half * 32];
        #pragma unroll
        for (int v = 0; v < 4; ++v) *(uint4*)(dst + v * 8) = *(uint4*)&tmp[v * 8];
    }
    {   // tbufT / pbufT [n][c]: n = tid&63, c-part = tid>>6
        int n = tid & 63, part = tid >> 6;
        const u16* srcT = &plds[n * 400 + 128 + part * 32];
        const u16* srcP = &plds[n * 400 + 256 + part * 32];
        u16* dT = &tbufT[(bN + n0 + n) * CI_ + part * 32];
        u16* dP = &pbufT[(bN + n0 + n) * CI_ + part * 32];
        #pragma unroll
        for (int v = 0; v < 2; ++v) {
            *(uint4*)(dT + v * 8 + 0)  = *(const uint4*)(srcT + v * 8);
            *(uint4*)(dP + v * 8 + 0)  = *(const uint4*)(srcP + v * 8);
            *(uint4*)(dT + v * 8 + 16) = *(const uint4*)(srcT + v * 8 + 16);
            *(uint4*)(dP + v * 8 + 16) = *(const uint4*)(srcP + v * 8 + 16);
        }
    }
}

// =====================================================================
// Kernel B: MFMA flash attention (unchanged from R3 except bf16 yt out).
// =====================================================================
#define PH_OFF(p) ((p) * 16384)
#define G_OFF(p)  (32768 + (p) * 20480)
#define PB_OFF    73728
#define MST_OFF   90112
#define LST_OFF   90368
#define SMEM_SZ   90624

__global__ __launch_bounds__(512) void attn_kernel(
    const u16* __restrict__ tbufT, const u16* __restrict__ pbufT,
    const u16* __restrict__ gbuf, u16* __restrict__ ytb)
{
    __shared__ __align__(16) char smem[SMEM_SZ];
    const int b   = blockIdx.y;
    const int q0  = blockIdx.x * 64;
    const int tid = threadIdx.x;
    const int w    = tid >> 6;
    const int lane = tid & 63;
    const int col  = lane & 15;
    const int quad = lane >> 4;
    const int wq   = w & 3;
    const int ms   = w >> 2;
    const int qw   = wq * 16;

    bf16x8 thf[4];
    {
        const u16* tb = tbufT + ((size_t)b * N_TOK + q0 + qw + col) * CI_;
        #pragma unroll
        for (int kc = 0; kc < 4; ++kc)
            thf[kc] = *(const bf16x8*)(tb + kc * 32 + quad * 8);
    }

    f32x4 yacc[8];
    #pragma unroll
    for (int i = 0; i < 8; ++i) yacc[i] = (f32x4){0.f, 0.f, 0.f, 0.f};
    float m_st = -3.0e38f, l_st = 0.f;

    const size_t bN = (size_t)b * N_TOK;
    const size_t bC = (size_t)b * CI_;

    for (int s = 0; s < 32; ++s) {
        __syncthreads();
        #pragma unroll
        for (int p = 0; p < 2; ++p) {
            const int m0p = (2 * s + p) * 64;
            #pragma unroll
            for (int i = 0; i < 2; ++i) {
                int cid = i * 512 + tid;
                int m = cid >> 4, h = cid & 15;
                uint4 v = *(const uint4*)(pbufT + (bN + m0p + m) * CI_ + h * 8);
                *(uint4*)(smem + PH_OFF(p) + m * 256 + ((h ^ (m & 15)) << 4)) = v;
            }
            #pragma unroll
            for (int i = 0; i < 2; ++i) {
                int cid = i * 512 + tid;
                int c = cid >> 3, h = cid & 7;
                uint4 v = *(const uint4*)(gbuf + (bC + c) * N_TOK + m0p + h * 8);
                *(uint4*)(smem + G_OFF(p) + c * 160 + ((h ^ (c & 7)) << 4)) = v;
            }
        }
        __syncthreads();

        f32x4 sacc[4];
        #pragma unroll
        for (int i = 0; i < 4; ++i) sacc[i] = (f32x4){0.f, 0.f, 0.f, 0.f};
        #pragma unroll
        for (int kc = 0; kc < 4; ++kc) {
            #pragma unroll
            for (int msub = 0; msub < 4; ++msub) {
                int m = msub * 16 + col;
                int h = kc * 4 + quad;
                bf16x8 af = *(const bf16x8*)(smem + PH_OFF(ms) + m * 256 + ((h ^ (m & 15)) << 4));
                sacc[msub] = __builtin_amdgcn_mfma_f32_16x16x32_bf16(af, thf[kc], sacc[msub], 0, 0, 0);
            }
        }

        float tmax = sacc[0][0];
        #pragma unroll
        for (int i = 0; i < 4; ++i)
            #pragma unroll
            for (int r = 0; r < 4; ++r) tmax = fmaxf(tmax, sacc[i][r]);
        tmax = fmaxf(tmax, __shfl_xor(tmax, 16));
        tmax = fmaxf(tmax, __shfl_xor(tmax, 32));
        float m_new = fmaxf(m_st, tmax);
        float p16[16], ps = 0.f;
        #pragma unroll
        for (int i = 0; i < 4; ++i)
            #pragma unroll
            for (int r = 0; r < 4; ++r) {
                float pv = __expf(sacc[i][r] - m_new);
                p16[i * 4 + r] = pv;
                ps += pv;
            }
        ps += __shfl_xor(ps, 16);
        ps += __shfl_xor(ps, 32);
        float alpha = __expf(m_st - m_new);
        l_st = l_st * alpha + ps;
        m_st = m_new;
        #pragma unroll
        for (int i = 0; i < 8; ++i) {
            yacc[i][0] *= alpha; yacc[i][1] *= alpha; yacc[i][2] *= alpha; yacc[i][3] *= alpha;
        }

        {
            char* pb = smem + PB_OFF + w * 2048 + col * 128;
            #pragma unroll
            for (int msub = 0; msub < 4; ++msub) {
                #pragma unroll
                for (int pr = 0; pr < 2; ++pr) {
                    u32 d = packbf(p16[msub * 4 + pr * 2], p16[msub * 4 + pr * 2 + 1]);
                    int h = msub * 2 + (quad >> 1);
                    *(u32*)(pb + ((h ^ (col & 7)) << 4) + (quad & 1) * 8 + pr * 4) = d;
                }
            }
        }
        __asm volatile("s_waitcnt lgkmcnt(0)" ::: "memory");

        bf16x8 pf[2];
        #pragma unroll
        for (int km = 0; km < 2; ++km) {
            int h = km * 4 + quad;
            pf[km] = *(const bf16x8*)(smem + PB_OFF + w * 2048 + col * 128 + ((h ^ (col & 7)) << 4));
        }
        #pragma unroll
        for (int csub = 0; csub < 8; ++csub) {
            #pragma unroll
            for (int km = 0; km < 2; ++km) {
                int c = csub * 16 + col;
                int h = km * 4 + quad;
                bf16x8 gf = *(const bf16x8*)(smem + G_OFF(ms) + c * 160 + ((h ^ (c & 7)) << 4));
                yacc[csub] = __builtin_amdgcn_mfma_f32_16x16x32_bf16(gf, pf[km], yacc[csub], 0, 0, 0);
            }
        }
    }

    __syncthreads();
    if (ms == 1) {
        char* mb = smem + wq * 8192 + col * 512;
        #pragma unroll
        for (int csub = 0; csub < 8; ++csub)
            *(f32x4*)(mb + (((csub * 4 + quad) ^ col) << 4)) = yacc[csub];
        if (quad == 0) {
            *(float*)(smem + MST_OFF + (wq * 16 + col) * 4) = m_st;
            *(float*)(smem + LST_OFF + (wq * 16 + col) * 4) = l_st;
        }
    }
    __syncthreads();
    if (ms == 0) {
        float m1 = *(const float*)(smem + MST_OFF + (wq * 16 + col) * 4);
        float l1 = *(const float*)(smem + LST_OFF + (wq * 16 + col) * 4);
        float M  = fmaxf(m_st, m1);
        float a0 = __expf(m_st - M), a1 = __expf(m1 - M);
        float li = 1.f / (l_st * a0 + l1 * a1);
        float s0 = a0 * li, s1 = a1 * li;
        const char* mb = smem + wq * 8192 + col * 512;
        u16* yo = ytb + (bN + q0 + qw + col) * CI_ + quad * 4;
        #pragma unroll
        for (int csub = 0; csub < 8; ++csub) {
            f32x4 y1 = *(const f32x4*)(mb + (((csub * 4 + quad) ^ col) << 4));
            uint2 pv;
            pv.x = packbf(yacc[csub][0] * s0 + y1[0] * s1, yacc[csub][1] * s0 + y1[1] * s1);
            pv.y = packbf(yacc[csub][2] * s0 + y1[2] * s1, yacc[csub][3] * s0 + y1[3] * s1);
            *(uint2*)(yo + csub * 16) = pv;
        }
    }
}

// =====================================================================
// Kernel C: MFMA outproj + fused BN-stats atomics.
// W_y[b][o][n] = sum_c wo[o][c]*yt[b][n][c] + bo[o]; wy fp32.
// Block 256 thr; n-tile 64; wave w: o in [64w, 64w+64). K=128.
// Both operands k-contiguous -> direct global frag loads, no LDS.
// =====================================================================
__global__ __launch_bounds__(256) void outproj_kernel(
    const u16* __restrict__ wbf, const float* __restrict__ canon,
    const u16* __restrict__ ytb, float* __restrict__ wy, float* __restrict__ stats)
{
    const int b  = blockIdx.y;
    const int n0 = blockIdx.x * 64;
    const int tid = threadIdx.x;
    const int w    = tid >> 6;
    const int lane = tid & 63;
    const int col  = lane & 15;
    const int quad = lane >> 4;
    const int ow   = w * 64;
    const u16* wo = wbf + 98304;
    const size_t bN = (size_t)b * N_TOK;

    f32x4 acc[4][4];
    #pragma unroll
    for (int i = 0; i < 4; ++i)
        #pragma unroll
        for (int j = 0; j < 4; ++j) acc[i][j] = (f32x4){0.f,0.f,0.f,0.f};

    #pragma unroll
    for (int kc = 0; kc < 4; ++kc) {
        bf16x8 bfr[4];
        #pragma unroll
        for (int nf = 0; nf < 4; ++nf)
            bfr[nf] = *(const bf16x8*)&ytb[(bN + n0 + nf * 16 + col) * CI_ + kc * 32 + quad * 8];
        #pragma unroll
        for (int os = 0; os < 4; ++os) {
            bf16x8 afr = *(const bf16x8*)&wo[(size_t)(ow + os * 16 + col) * CI_ + kc * 32 + quad * 8];
            #pragma unroll
            for (int nf = 0; nf < 4; ++nf)
                acc[os][nf] = __builtin_amdgcn_mfma_f32_16x16x32_bf16(afr, bfr[nf], acc[os][nf], 0, 0, 0);
        }
    }

    float s1[4][4], s2[4][4];
    #pragma unroll
    for (int os = 0; os < 4; ++os) {
        int o0 = ow + os * 16 + quad * 4;
        float bb[4];
        #pragma unroll
        for (int i = 0; i < 4; ++i) { bb[i] = canon[131456 + o0 + i]; s1[os][i] = 0.f; s2[os][i] = 0.f; }
        #pragma unroll
        for (int nf = 0; nf < 4; ++nf) {
            #pragma unroll
            for (int i = 0; i < 4; ++i) {
                float v = acc[os][nf][i] + bb[i];
                wy[((size_t)b * C_IN + o0 + i) * N_TOK + n0 + nf * 16 + col] = v;
                s1[os][i] += v;
                s2[os][i] += v * v;
            }
        }
    }
    // reduce over the 16 col-lanes, then one atomic per (o) from col==0
    #pragma unroll
    for (int os = 0; os < 4; ++os)
        #pragma unroll
        for (int i = 0; i < 4; ++i) {
            float a = s1[os][i], q = s2[os][i];
            #pragma unroll
            for (int off = 8; off; off >>= 1) {
                a += __shfl_xor(a, off);
                q += __shfl_xor(q, off);
            }
            s1[os][i] = a; s2[os][i] = q;
        }
    if (col == 0) {
        #pragma unroll
        for (int os = 0; os < 4; ++os)
            #pragma unroll
            for (int i = 0; i < 4; ++i) {
                int o = ow + os * 16 + quad * 4 + i;
                atomicAdd(&stats[o], s1[os][i]);
                atomicAdd(&stats[256 + o], s2[os][i]);
            }
    }
}

// ===================== BN finalize =====================
__global__ __launch_bounds__(256) void bnfinal_kernel(
    const float* __restrict__ stats, float* __restrict__ meanv, float* __restrict__ rstdv)
{
    int o = threadIdx.x;
    float mean = stats[o] * (1.f / 16384.f);
    float var  = stats[256 + o] * (1.f / 16384.f) - mean * mean;
    meanv[o] = mean;
    rstdv[o] = rsqrtf(var + 1e-5f);
}

// ===================== BN apply + residual =====================
__global__ __launch_bounds__(256) void bnorm_kernel(
    const float* __restrict__ wy, const void* __restrict__ x,
    const float* __restrict__ meanv, const float* __restrict__ rstdv,
    const float* __restrict__ canon, const int* __restrict__ flagp,
    void* __restrict__ outv)
{
    const int flag = *flagp;
    size_t base = ((size_t)blockIdx.x * 256 + threadIdx.x) * 8;
    int o = (int)((base >> 12) & 255);
    float m = meanv[o], r = rstdv[o];
    float gm = canon[131712 + o], bt = canon[131968 + o];
    float4 v0 = *(const float4*)&wy[base];
    float4 v1 = *(const float4*)&wy[base + 4];
    float xf[8]; load8(x, base, flag, xf);
    float ov[8];
    ov[0] = (v0.x - m) * r * gm + bt + xf[0];
    ov[1] = (v0.y - m) * r * gm + bt + xf[1];
    ov[2] = (v0.z - m) * r * gm + bt + xf[2];
    ov[3] = (v0.w - m) * r * gm + bt + xf[3];
    ov[4] = (v1.x - m) * r * gm + bt + xf[4];
    ov[5] = (v1.y - m) * r * gm + bt + xf[5];
    ov[6] = (v1.z - m) * r * gm + bt + xf[6];
    ov[7] = (v1.w - m) * r * gm + bt + xf[7];
    if (flag) {
        float* op = (float*)outv + base;
        *(float4*)op       = *(float4*)&ov[0];
        *(float4*)(op + 4) = *(float4*)&ov[4];
    } else {
        uint4 res;
        res.x = packbf(ov[0], ov[1]);
        res.y = packbf(ov[2], ov[3]);
        res.z = packbf(ov[4], ov[5]);
        res.w = packbf(ov[6], ov[7]);
        *(uint4*)((u16*)outv + base) = res;
    }
}

extern "C" void kernel_launch(void* const* d_in, const int* in_sizes, int n_in,
                              void* d_out, int out_size, void* d_ws, size_t ws_size,
                              hipStream_t stream)
{
    const void* x   = d_in[0];
    const void* w_g = d_in[1];
    const void* b_g = d_in[2];
    const void* w_t = d_in[3];
    const void* b_t = d_in[4];
    const void* w_p = d_in[5];
    const void* b_p = d_in[6];
    const void* w_o = d_in[7];
    const void* b_o = d_in[8];
    const void* gm  = d_in[9];
    const void* bt  = d_in[10];

    char* base = (char*)d_ws;
    float* canon    = (float*)base;                    // 132224 f32 = 528896 B
    u16*   canon_bf = (u16*)(base + 528896);           // 131072 u16 = 262144 B
    int*   flagp    = (int*)(base + 791040);
    float* stats    = (float*)(base + 791296);         // 512 f32 = 2048 B
    u16*   gbuf     = (u16*)(base + 1048576);          // 4 MB bf16 [b][c][n]
    u16*   tbufT    = (u16*)(base + 5242880);          // 4 MB bf16 [b][n][c]
    u16*   pbufT    = (u16*)(base + 9437184);          // 4 MB bf16 [b][n][c]
    u16*   ytb      = (u16*)(base + 13631488);         // 4 MB bf16 [b][n][c]
    float* wy       = (float*)(base + 17825792);       // 16 MB f32 [b][o][n]
    float* meanv    = (float*)(base + 34603008);
    float* rstdv    = (float*)(base + 34604032);

    detect_kernel<<<1, 64, 0, stream>>>((const u16*)w_g, flagp);
    convert_params_kernel<<<517, 256, 0, stream>>>(w_g, w_t, w_p, w_o, b_g, b_t, b_p, b_o,
                                                   gm, bt, flagp, canon, canon_bf);
    hipMemsetAsync(stats, 0, 2048, stream);
    proj_kernel<<<dim3(64, 4), 256, 0, stream>>>(x, canon, canon_bf, flagp, gbuf, tbufT, pbufT);
    attn_kernel<<<dim3(64, 4), 512, 0, stream>>>(tbufT, pbufT, gbuf, ytb);
    outproj_kernel<<<dim3(64, 4), 256, 0, stream>>>(canon_bf, canon, ytb, wy, stats);
    bnfinal_kernel<<<1, 256, 0, stream>>>(stats, meanv, rstdv);
    bnorm_kernel<<<2048, 256, 0, stream>>>(wy, x, meanv, rstdv, canon, flagp, d_out);
}